// Round 5
// baseline (347.571 us; speedup 1.0000x reference)
//
#include <hip/hip_runtime.h>

// FusedGromovWasserstein — 3 kernels:
//  prep_w32: W1,W2 f32 -> pre-split bf16 hi/lo 32x32x16-MFMA B-fragments in d_ws
//  fgw_proj: 2 batches/block, 512 thr (8 waves; wave = 32 cols x both batches);
//            2-layer MLP via mfma_32x32x16 (x-hi only, W hi+lo 2-product);
//            C via G=pq@pr^T MFMA + norms
//  fgw_sink: 1 wave/batch, barrier-free; DPP/swizzle reduces; 5x10 sinkhorn
// Outputs flat: [sigmoid(-cost) 8192][T 8192*256][C 8192*256][cost 8192].

#define OFF_T   8192
#define OFF_C   2105344
#define OFF_CST 4202496

typedef float  f32x4  __attribute__((ext_vector_type(4)));
typedef float  f32x16 __attribute__((ext_vector_type(16)));
typedef short  s16x8  __attribute__((ext_vector_type(8)));

__device__ __forceinline__ unsigned short f2bf(float f) {
  unsigned int u = __float_as_uint(f);
  u += 0x7FFFu + ((u >> 16) & 1u);          // round-to-nearest-even
  return (unsigned short)(u >> 16);
}
__device__ __forceinline__ float bf2f(unsigned short h) {
  return __uint_as_float(((unsigned int)h) << 16);
}

// ---- cross-lane reduction helpers ----
template <int CTRL>
__device__ __forceinline__ float dpp_add(float x) {
  return x + __int_as_float(__builtin_amdgcn_update_dpp(
      0, __float_as_int(x), CTRL, 0xf, 0xf, true));
}
template <int CTRL>
__device__ __forceinline__ float dpp_max(float x) {
  return fmaxf(x, __int_as_float(__builtin_amdgcn_update_dpp(
      0, __float_as_int(x), CTRL, 0xf, 0xf, true)));
}
__device__ __forceinline__ float row16_sum(float x) {
  x = dpp_add<0xB1>(x);  x = dpp_add<0x4E>(x);
  x = dpp_add<0x124>(x); x = dpp_add<0x128>(x);
  return x;
}
__device__ __forceinline__ float row16_max(float x) {
  x = dpp_max<0xB1>(x);  x = dpp_max<0x4E>(x);
  x = dpp_max<0x124>(x); x = dpp_max<0x128>(x);
  return x;
}
__device__ __forceinline__ float xor16_add(float x) {
  return x + __int_as_float(__builtin_amdgcn_ds_swizzle(__float_as_int(x), 0x401F));
}
__device__ __forceinline__ float xor16_max(float x) {
  return fmaxf(x, __int_as_float(__builtin_amdgcn_ds_swizzle(__float_as_int(x), 0x401F)));
}
__device__ __forceinline__ float xor32_add(float x) { return x + __shfl_xor(x, 32); }
__device__ __forceinline__ float xor32_max(float x) { return fmaxf(x, __shfl_xor(x, 32)); }

// ---------------------------------------------------------------------------
// prep_w32: 16384 fragments (2 layers x 16 ksteps x 8 colgroups x 64 lanes).
// Fragment fid holds W[col = cg*32 + (lane&31)][k = s*16 + (lane>>5)*8 + e].
__global__ __launch_bounds__(256, 1)
void prep_w32(const float* __restrict__ W1, const float* __restrict__ W2,
              unsigned int* __restrict__ wh, unsigned int* __restrict__ wl)
{
  const int fid  = blockIdx.x * 256 + threadIdx.x;   // 0..16383
  const int l    = fid >> 13;
  const int s    = (fid >> 9) & 15;
  const int cg   = (fid >> 6) & 7;
  const int lane = fid & 63;
  const int col  = cg * 32 + (lane & 31);
  const int k0   = s * 16 + ((lane >> 5) << 3);
  const float* W = l ? W2 : W1;
  const float* src = W + ((size_t)col << 8) + k0;
  float4 a = *(const float4*)src;
  float4 b = *(const float4*)(src + 4);
  float f[8] = {a.x, a.y, a.z, a.w, b.x, b.y, b.z, b.w};
  unsigned int uh[4], ul[4];
  #pragma unroll
  for (int i = 0; i < 4; ++i) {
    unsigned short h0 = f2bf(f[2*i]),            h1 = f2bf(f[2*i+1]);
    unsigned short l0 = f2bf(f[2*i]   - bf2f(h0));
    unsigned short l1 = f2bf(f[2*i+1] - bf2f(h1));
    uh[i] = (unsigned)h0 | ((unsigned)h1 << 16);
    ul[i] = (unsigned)l0 | ((unsigned)l1 << 16);
  }
  uint4 vh = {uh[0], uh[1], uh[2], uh[3]};
  uint4 vl = {ul[0], ul[1], ul[2], ul[3]};
  ((uint4*)wh)[fid] = vh;
  ((uint4*)wl)[fid] = vl;
}

// ---------------------------------------------------------------------------
// fgw_proj: 2 batches/block, 512 threads. LDS per batch: x-hi tile 16KB
// (rows 0-15 q, 16-31 r; row stride 512B; XOR swizzle ((row&7)<<4)).
// normL [2][8][32] f32 at float idx 8192. Gp overlays batch0 tile after GEMM.
__global__ __launch_bounds__(512, 6)
void fgw_proj(const float* __restrict__ g_q,  const float* __restrict__ g_r,
              const unsigned short* __restrict__ wh,
              const unsigned short* __restrict__ wl,
              const float* __restrict__ g_b1, const float* __restrict__ g_b2,
              float* __restrict__ g_out)
{
  __shared__ __align__(16) float smemf[8704];   // 34,816 B
  char* sm = (char*)smemf;
  float* normL = smemf + 8192;                  // 512 floats
  const int bId0 = blockIdx.x * 2;
  const int tid  = threadIdx.x;
  const int lane = tid & 63, wid = tid >> 6;    // wid 0..7
  const int cl   = lane & 31, half = lane >> 5; // A-row / D-col, k-half

  // ---- stage 2 batches as bf16-hi (2048 float4-slots / 512 thr) ----
  #pragma unroll
  for (int j = 0; j < 4; ++j) {
    int idx = (j << 9) + tid;          // 0..2047
    int bb  = idx >> 10;
    int t   = idx & 1023;
    int r   = t >> 6;                  // row 0..15
    int sg  = t & 63;                  // float4 segment
    int off = ((sg << 3) ^ ((r & 7) << 4));
    char* xb = sm + bb * 16384;
    const float* xq = g_q + (size_t)(bId0 + bb) * 4096 + (r << 8) + (sg << 2);
    const float* xr = g_r + (size_t)(bId0 + bb) * 4096 + (r << 8) + (sg << 2);
    float4 v0 = *(const float4*)xq;
    float4 v1 = *(const float4*)xr;
    {
      unsigned int* ph = (unsigned int*)(xb + r * 512 + off);
      ph[0] = (unsigned)f2bf(v0.x) | ((unsigned)f2bf(v0.y) << 16);
      ph[1] = (unsigned)f2bf(v0.z) | ((unsigned)f2bf(v0.w) << 16);
    }
    {
      unsigned int* ph = (unsigned int*)(xb + (16 + r) * 512 + off);
      ph[0] = (unsigned)f2bf(v1.x) | ((unsigned)f2bf(v1.y) << 16);
      ph[1] = (unsigned)f2bf(v1.z) | ((unsigned)f2bf(v1.w) << 16);
    }
  }
  __syncthreads();

  // ---- two layers: out = act(X @ W^T + b); wave wid -> cols [32*wid, +32),
  //      both batches; x-hi only, W hi+lo (2-product split) ----
  for (int layer = 0; layer < 2; ++layer) {
    f32x16 acc0 = {0.f}, acc1 = {0.f};
    #pragma unroll
    for (int i = 0; i < 16; ++i) { acc0[i] = 0.f; acc1[i] = 0.f; }

    const float* bl_ = layer ? g_b2 : g_b1;
    #pragma unroll 4
    for (int ks = 0; ks < 16; ++ks) {
      const int aoff = (((ks << 5) + (half << 4)) ^ ((cl & 7) << 4));
      s16x8 a0 = *(const s16x8*)(sm +         cl * 512 + aoff);
      s16x8 a1 = *(const s16x8*)(sm + 16384 + cl * 512 + aoff);
      const size_t fb = ((((size_t)layer * 16 + ks) * 8 + wid) * 64 + lane) * 8;
      s16x8 bh = *(const s16x8*)(wh + fb);
      s16x8 bl = *(const s16x8*)(wl + fb);
      acc0 = __builtin_amdgcn_mfma_f32_32x32x16_bf16(a0, bh, acc0, 0, 0, 0);
      acc0 = __builtin_amdgcn_mfma_f32_32x32x16_bf16(a0, bl, acc0, 0, 0, 0);
      acc1 = __builtin_amdgcn_mfma_f32_32x32x16_bf16(a1, bh, acc1, 0, 0, 0);
      acc1 = __builtin_amdgcn_mfma_f32_32x32x16_bf16(a1, bl, acc1, 0, 0, 0);
    }
    __syncthreads();   // all x reads done before in-place overwrite

    const float bv = bl_[(wid << 5) + cl];   // D col = wid*32 + cl
    const int colb = ((((wid << 5) + cl) << 1));

    if (layer == 0) {
      #pragma unroll
      for (int reg = 0; reg < 16; ++reg) {
        int rr  = (reg & 3) + ((reg >> 2) << 3) + (half << 2);
        int off = colb ^ ((rr & 7) << 4);
        float h0 = fmaxf(acc0[reg] + bv, 0.f);
        float h1 = fmaxf(acc1[reg] + bv, 0.f);
        *(unsigned short*)(sm +         rr * 512 + off) = f2bf(h0);
        *(unsigned short*)(sm + 16384 + rr * 512 + off) = f2bf(h1);
      }
      __syncthreads();
    } else {
      // layer 2: per-row norm partials (over wave's 32 cols) + write p-hi
      #pragma unroll
      for (int reg = 0; reg < 16; ++reg) {
        int rr  = (reg & 3) + ((reg >> 2) << 3) + (half << 2);
        int off = colb ^ ((rr & 7) << 4);
        float p0 = acc0[reg] + bv;
        float p1 = acc1[reg] + bv;
        float s0 = xor16_add(row16_sum(p0 * p0));   // sum over 32 cols
        float s1 = xor16_add(row16_sum(p1 * p1));
        if (cl == 0) {
          normL[(0 * 8 + wid) * 32 + rr] = s0;
          normL[(1 * 8 + wid) * 32 + rr] = s1;
        }
        *(unsigned short*)(sm +         rr * 512 + off) = f2bf(p0);
        *(unsigned short*)(sm + 16384 + rr * 512 + off) = f2bf(p1);
      }
      __syncthreads();
    }
  }

  // ---- G = pq @ pr^T per batch (16x16x32 MFMA, p-hi only) ----
  const int fr = lane & 15, fg = lane >> 4;
  f32x4 accG = {0.f, 0.f, 0.f, 0.f};
  const int bbG = wid >> 2;
  {
    char* xb = sm + bbG * 16384;
    #pragma unroll
    for (int kk = 0; kk < 2; ++kk) {
      int ks16 = ((wid & 3) << 1) + kk;
      int koff = ((ks16 << 6) + (fg << 4)) ^ ((fr & 7) << 4);
      s16x8 aq = *(const s16x8*)(xb +        fr * 512 + koff);
      s16x8 br = *(const s16x8*)(xb + (16 + fr) * 512 + koff);
      accG = __builtin_amdgcn_mfma_f32_16x16x32_bf16(aq, br, accG, 0, 0, 0);
    }
  }
  __syncthreads();                       // all G-input reads complete
  float* Gp = smemf;                     // [2][4][256] overlays batch0 tile
  #pragma unroll
  for (int j = 0; j < 4; ++j)
    Gp[(bbG * 4 + (wid & 3)) * 256 + ((fg << 2) + j) * 16 + fr] = accG[j];
  __syncthreads();

  // ---- C = sqrt(max(nq + nr - 2G, 1e-6)); thr 0-255 bb0, 256-511 bb1 ----
  {
    const int bbC = tid >> 8;
    const int t2  = tid & 255;
    const int tk  = t2 >> 4, tm = t2 & 15;
    float Gv = Gp[(bbC*4+0)*256 + tk*16 + tm] + Gp[(bbC*4+1)*256 + tk*16 + tm]
             + Gp[(bbC*4+2)*256 + tk*16 + tm] + Gp[(bbC*4+3)*256 + tk*16 + tm];
    float nq = 0.f, nr = 0.f;
    #pragma unroll
    for (int w = 0; w < 8; ++w) {
      nq += normL[(bbC*8+w)*32 + tk];
      nr += normL[(bbC*8+w)*32 + 16 + tm];
    }
    float d2 = nq + nr - 2.0f * Gv;
    g_out[OFF_C + (size_t)(bId0 + bbC) * 256 + t2] = sqrtf(fmaxf(d2, 1e-6f));
  }
}

// ---------------------------------------------------------------------------
// fgw_sink: 1 wave per batch, 4 waves/block, zero barriers.
// Lane layout: m = lane&15 (column), k_j = 4*(lane>>4)+j (4 rows per lane).
__global__ __launch_bounds__(256, 4)
void fgw_sink(const float* __restrict__ g_mq, const float* __restrict__ g_mr,
              const float* __restrict__ g_cq, const float* __restrict__ g_cr,
              const float* __restrict__ g_leps, float* __restrict__ g_out)
{
  __shared__ __align__(16) float sk[4 * 1408];
  const int tid  = threadIdx.x, lane = tid & 63, w = tid >> 6;
  const int batch = blockIdx.x * 4 + w;
  const int m = lane & 15, g = lane >> 4;
  float* L     = sk + w * 1408;
  float* SqL   = L;        float* SrL   = L + 320;
  float* TtL   = L + 640;  float* M1L   = L + 960;
  float* lmuL  = L + 1280; float* muL   = L + 1296;
  float* cqxL  = L + 1312; float* cqyL  = L + 1328;
  float* crxL  = L + 1344; float* cryL  = L + 1360;
  float* trowL = L + 1376; float* tcolL = L + 1392;

  float mqv = g_mq[(size_t)batch * 16 + m];
  float mrv = g_mr[(size_t)batch * 16 + m];
  float mu_m = mqv / (row16_sum(mqv) + 1e-8f);
  float nu_m = mrv / (row16_sum(mrv) + 1e-8f);
  float lmu_m = __logf(fmaxf(mu_m, 1e-8f));
  float lnu_m = __logf(fmaxf(nu_m, 1e-8f));
  float cqx_m = g_cq[(size_t)batch * 32 + 2 * m];
  float cqy_m = g_cq[(size_t)batch * 32 + 2 * m + 1];
  float crx_m = g_cr[(size_t)batch * 32 + 2 * m];
  float cry_m = g_cr[(size_t)batch * 32 + 2 * m + 1];
  if (g == 0) {
    lmuL[m] = lmu_m;  muL[m] = mu_m;
    cqxL[m] = cqx_m;  cqyL[m] = cqy_m;
    crxL[m] = crx_m;  cryL[m] = cry_m;
  }
  f32x4 lmu_j = *(const f32x4*)(lmuL + 4 * g);
  f32x4 mu_j  = *(const f32x4*)(muL  + 4 * g);
  f32x4 cqxj  = *(const f32x4*)(cqxL + 4 * g);
  f32x4 cqyj  = *(const f32x4*)(cqyL + 4 * g);
  f32x4 crxj  = *(const f32x4*)(crxL + 4 * g);
  f32x4 cryj  = *(const f32x4*)(cryL + 4 * g);

  float Sq2r[4], Sr2r[4];
  #pragma unroll
  for (int j = 0; j < 4; ++j) {
    float dx = cqxj[j] - cqx_m, dy = cqyj[j] - cqy_m;
    float d2 = fmaxf(dx * dx + dy * dy, 1e-6f);
    SqL[(4 * g + j) * 20 + m] = sqrtf(d2);
    Sq2r[j] = d2;
    float ex = crxj[j] - crx_m, ey = cryj[j] - cry_m;
    float e2 = fmaxf(ex * ex + ey * ey, 1e-6f);
    SrL[(4 * g + j) * 20 + m] = sqrtf(e2);
    Sr2r[j] = e2;
  }

  float C_[4];
  const float* Cp = g_out + OFF_C + (size_t)batch * 256;
  #pragma unroll
  for (int j = 0; j < 4; ++j) C_[j] = Cp[(4 * g + j) * 16 + m];
  float eps = fminf(fmaxf(__expf(g_leps[0]), 0.01f), 0.5f);
  const float inv_eps = 1.0f / eps;
  const float rho = 0.1f / (0.1f + eps);
  float rlmu[4];
  #pragma unroll
  for (int j = 0; j < 4; ++j) rlmu[j] = rho * lmu_j[j];
  const float rlnu = rho * lnu_m;
  float T_[4];
  #pragma unroll
  for (int j = 0; j < 4; ++j) T_[j] = mu_j[j] * nu_m;

  float Cf[4], logK[4], KM[4], Mx[4], u_[4], v = 0.f;

  for (int it = 0; it < 5; ++it) {
    float trow_j[4];
    #pragma unroll
    for (int j = 0; j < 4; ++j) trow_j[j] = row16_sum(T_[j]);
    float tc = xor32_add(xor16_add(T_[0] + T_[1] + T_[2] + T_[3]));
    if (m == 0) { f32x4 tv = {trow_j[0], trow_j[1], trow_j[2], trow_j[3]};
                  *(f32x4*)(trowL + 4 * g) = tv; }
    if (g == 0) tcolL[m] = tc;
    { f32x4 tv = {T_[0], T_[1], T_[2], T_[3]};
      *(f32x4*)(TtL + m * 20 + 4 * g) = tv; }

    float trow_m = trowL[m];
    float t1_[4];
    #pragma unroll
    for (int j = 0; j < 4; ++j) t1_[j] = row16_sum(Sq2r[j] * trow_m);
    f32x4 tcv = *(const f32x4*)(tcolL + 4 * g);
    float p2 = tcv[0] * Sr2r[0] + tcv[1] * Sr2r[1] + tcv[2] * Sr2r[2] + tcv[3] * Sr2r[3];
    float t2_ = xor32_add(xor16_add(p2));

    float M1r[4] = {0.f, 0.f, 0.f, 0.f};
    #pragma unroll
    for (int l = 0; l < 16; ++l) {
      f32x4 t4 = *(const f32x4*)(TtL + l * 20 + 4 * g);
      float srv = SrL[l * 20 + m];
      M1r[0] += t4[0] * srv; M1r[1] += t4[1] * srv;
      M1r[2] += t4[2] * srv; M1r[3] += t4[3] * srv;
    }
    #pragma unroll
    for (int j = 0; j < 4; ++j) M1L[(4 * g + j) * 20 + m] = M1r[j];
    float t3_[4] = {0.f, 0.f, 0.f, 0.f};
    #pragma unroll
    for (int l = 0; l < 16; ++l) {
      f32x4 sq4 = *(const f32x4*)(SqL + l * 20 + 4 * g);
      float m1v = M1L[l * 20 + m];
      t3_[0] += sq4[0] * m1v; t3_[1] += sq4[1] * m1v;
      t3_[2] += sq4[2] * m1v; t3_[3] += sq4[3] * m1v;
    }

    #pragma unroll
    for (int j = 0; j < 4; ++j) {
      float lgw = t1_[j] + t2_ - 2.0f * t3_[j];
      Cf[j]   = 0.5f * C_[j] + 0.5f * lgw;
      logK[j] = -inv_eps * Cf[j];
      Mx[j]   = row16_max(logK[j]);     // static row shift (underflow-safe)
      KM[j]   = logK[j] - Mx[j];
    }

    v = 0.f;
    #pragma unroll 1
    for (int s = 0; s < 10; ++s) {
      #pragma unroll
      for (int j = 0; j < 4; ++j) {
        float sj = row16_sum(__expf(KM[j] + v));
        u_[j] = rlmu[j] - rho * (Mx[j] + __logf(sj));
      }
      float x0 = logK[0] + u_[0], x1 = logK[1] + u_[1];
      float x2 = logK[2] + u_[2], x3 = logK[3] + u_[3];
      float mx = fmaxf(fmaxf(x0, x1), fmaxf(x2, x3));
      mx = xor32_max(xor16_max(mx));
      float ss = __expf(x0 - mx) + __expf(x1 - mx) + __expf(x2 - mx) + __expf(x3 - mx);
      ss = xor32_add(xor16_add(ss));
      v = rlnu - rho * (mx + __logf(ss));
    }
    #pragma unroll
    for (int j = 0; j < 4; ++j) T_[j] = __expf(u_[j] + logK[j] + v);
  }

  float cp = T_[0] * Cf[0] + T_[1] * Cf[1] + T_[2] * Cf[2] + T_[3] * Cf[3];
  cp = xor32_add(xor16_add(row16_sum(cp)));
  float* To = g_out + OFF_T + (size_t)batch * 256;
  #pragma unroll
  for (int j = 0; j < 4; ++j) To[(4 * g + j) * 16 + m] = T_[j];
  if (lane == 0) {
    g_out[batch] = 1.0f / (1.0f + __expf(cp));   // sigmoid(-cost)
    g_out[OFF_CST + batch] = cp;
  }
}

extern "C" void kernel_launch(void* const* d_in, const int* in_sizes, int n_in,
                              void* d_out, int out_size, void* d_ws, size_t ws_size,
                              hipStream_t stream) {
  (void)in_sizes; (void)n_in; (void)out_size; (void)ws_size;
  unsigned int*   wh32 = (unsigned int*)d_ws;
  unsigned int*   wl32 = wh32 + 65536;                 // 262,144 B each
  unsigned short* wh   = (unsigned short*)wh32;
  unsigned short* wl   = (unsigned short*)wl32;

  prep_w32<<<dim3(64), dim3(256), 0, stream>>>(
      (const float*)d_in[6], (const float*)d_in[8], wh32, wl32);
  fgw_proj<<<dim3(4096), dim3(512), 0, stream>>>(
      (const float*)d_in[0], (const float*)d_in[1], wh, wl,
      (const float*)d_in[7], (const float*)d_in[9], (float*)d_out);
  fgw_sink<<<dim3(2048), dim3(256), 0, stream>>>(
      (const float*)d_in[2], (const float*)d_in[3],
      (const float*)d_in[4], (const float*)d_in[5],
      (const float*)d_in[10], (float*)d_out);
}

// Round 6
// 277.986 us; speedup vs baseline: 1.2503x; 1.2503x over previous
//
#include <hip/hip_runtime.h>

// FusedGromovWasserstein — 3 kernels:
//  prep_w32: W1,W2 f32 -> pre-split bf16 hi/lo 32x32x16-MFMA B-fragments in d_ws
//  fgw_proj: 4 batches/block, 512 thr (8 waves; wave = 32 cols x 4 batches);
//            2-layer MLP via mfma_32x32x16 (x-hi only, W hi+lo 2-product),
//            W register double-buffer; C via G=pq@pr^T MFMA + norms
//  fgw_sink: 1 wave/batch, barrier-free; DPP/swizzle reduces; 5x10 sinkhorn
// Outputs flat: [sigmoid(-cost) 8192][T 8192*256][C 8192*256][cost 8192].

#define OFF_T   8192
#define OFF_C   2105344
#define OFF_CST 4202496

typedef float  f32x4  __attribute__((ext_vector_type(4)));
typedef float  f32x16 __attribute__((ext_vector_type(16)));
typedef short  s16x8  __attribute__((ext_vector_type(8)));

__device__ __forceinline__ unsigned short f2bf(float f) {
  unsigned int u = __float_as_uint(f);
  u += 0x7FFFu + ((u >> 16) & 1u);          // round-to-nearest-even
  return (unsigned short)(u >> 16);
}
__device__ __forceinline__ float bf2f(unsigned short h) {
  return __uint_as_float(((unsigned int)h) << 16);
}

// ---- cross-lane reduction helpers ----
template <int CTRL>
__device__ __forceinline__ float dpp_add(float x) {
  return x + __int_as_float(__builtin_amdgcn_update_dpp(
      0, __float_as_int(x), CTRL, 0xf, 0xf, true));
}
template <int CTRL>
__device__ __forceinline__ float dpp_max(float x) {
  return fmaxf(x, __int_as_float(__builtin_amdgcn_update_dpp(
      0, __float_as_int(x), CTRL, 0xf, 0xf, true)));
}
__device__ __forceinline__ float row16_sum(float x) {
  x = dpp_add<0xB1>(x);  x = dpp_add<0x4E>(x);
  x = dpp_add<0x124>(x); x = dpp_add<0x128>(x);
  return x;
}
__device__ __forceinline__ float row16_max(float x) {
  x = dpp_max<0xB1>(x);  x = dpp_max<0x4E>(x);
  x = dpp_max<0x124>(x); x = dpp_max<0x128>(x);
  return x;
}
__device__ __forceinline__ float xor16_add(float x) {
  return x + __int_as_float(__builtin_amdgcn_ds_swizzle(__float_as_int(x), 0x401F));
}
__device__ __forceinline__ float xor16_max(float x) {
  return fmaxf(x, __int_as_float(__builtin_amdgcn_ds_swizzle(__float_as_int(x), 0x401F)));
}
__device__ __forceinline__ float xor32_add(float x) { return x + __shfl_xor(x, 32); }
__device__ __forceinline__ float xor32_max(float x) { return fmaxf(x, __shfl_xor(x, 32)); }

// ---------------------------------------------------------------------------
// prep_w32: 16384 fragments (2 layers x 16 ksteps x 8 colgroups x 64 lanes).
// Fragment fid holds W[col = cg*32 + (lane&31)][k = s*16 + (lane>>5)*8 + e].
__global__ __launch_bounds__(256, 1)
void prep_w32(const float* __restrict__ W1, const float* __restrict__ W2,
              unsigned int* __restrict__ wh, unsigned int* __restrict__ wl)
{
  const int fid  = blockIdx.x * 256 + threadIdx.x;   // 0..16383
  const int l    = fid >> 13;
  const int s    = (fid >> 9) & 15;
  const int cg   = (fid >> 6) & 7;
  const int lane = fid & 63;
  const int col  = cg * 32 + (lane & 31);
  const int k0   = s * 16 + ((lane >> 5) << 3);
  const float* W = l ? W2 : W1;
  const float* src = W + ((size_t)col << 8) + k0;
  float4 a = *(const float4*)src;
  float4 b = *(const float4*)(src + 4);
  float f[8] = {a.x, a.y, a.z, a.w, b.x, b.y, b.z, b.w};
  unsigned int uh[4], ul[4];
  #pragma unroll
  for (int i = 0; i < 4; ++i) {
    unsigned short h0 = f2bf(f[2*i]),            h1 = f2bf(f[2*i+1]);
    unsigned short l0 = f2bf(f[2*i]   - bf2f(h0));
    unsigned short l1 = f2bf(f[2*i+1] - bf2f(h1));
    uh[i] = (unsigned)h0 | ((unsigned)h1 << 16);
    ul[i] = (unsigned)l0 | ((unsigned)l1 << 16);
  }
  uint4 vh = {uh[0], uh[1], uh[2], uh[3]};
  uint4 vl = {ul[0], ul[1], ul[2], ul[3]};
  ((uint4*)wh)[fid] = vh;
  ((uint4*)wl)[fid] = vl;
}

// ---------------------------------------------------------------------------
// fgw_proj: 4 batches/block, 512 threads. LDS: 4 x 16KB x-hi tiles
// (rows 0-15 q, 16-31 r; row stride 512B; XOR swizzle ((row&7)<<4)),
// normL [4][8][32] f32 at float idx 16384. Gp overlays batch0 tile after GEMM.
__global__ __launch_bounds__(512, 4)
void fgw_proj(const float* __restrict__ g_q,  const float* __restrict__ g_r,
              const unsigned short* __restrict__ wh,
              const unsigned short* __restrict__ wl,
              const float* __restrict__ g_b1, const float* __restrict__ g_b2,
              float* __restrict__ g_out)
{
  __shared__ __align__(16) float smemf[17408];   // 69,632 B
  char* sm = (char*)smemf;
  float* normL = smemf + 16384;                  // 1024 floats
  const int bId0 = blockIdx.x * 4;
  const int tid  = threadIdx.x;
  const int lane = tid & 63, wid = tid >> 6;     // wid 0..7
  const int cl   = lane & 31, half = lane >> 5;  // A-row / D-col, k-half

  // ---- stage 4 batches as bf16-hi; non-temporal (read-once stream) ----
  #pragma unroll
  for (int j = 0; j < 8; ++j) {
    int idx = (j << 9) + tid;          // 0..4095
    int bb  = idx >> 10;
    int t   = idx & 1023;
    int r   = t >> 6;                  // row 0..15
    int sg  = t & 63;                  // float4 segment
    int off = ((sg << 3) ^ ((r & 7) << 4));
    char* xb = sm + bb * 16384;
    const f32x4* xq = (const f32x4*)(g_q + (size_t)(bId0 + bb) * 4096 + (r << 8) + (sg << 2));
    const f32x4* xr = (const f32x4*)(g_r + (size_t)(bId0 + bb) * 4096 + (r << 8) + (sg << 2));
    f32x4 v0 = __builtin_nontemporal_load(xq);
    f32x4 v1 = __builtin_nontemporal_load(xr);
    {
      unsigned int* ph = (unsigned int*)(xb + r * 512 + off);
      ph[0] = (unsigned)f2bf(v0[0]) | ((unsigned)f2bf(v0[1]) << 16);
      ph[1] = (unsigned)f2bf(v0[2]) | ((unsigned)f2bf(v0[3]) << 16);
    }
    {
      unsigned int* ph = (unsigned int*)(xb + (16 + r) * 512 + off);
      ph[0] = (unsigned)f2bf(v1[0]) | ((unsigned)f2bf(v1[1]) << 16);
      ph[1] = (unsigned)f2bf(v1[2]) | ((unsigned)f2bf(v1[3]) << 16);
    }
  }
  __syncthreads();

  // ---- two layers: out = act(X @ W^T + b); wave wid -> cols [32*wid, +32),
  //      4 batches; x-hi only, W hi+lo (2-product split); W reg dbuf ----
  for (int layer = 0; layer < 2; ++layer) {
    f32x16 acc0, acc1, acc2, acc3;
    #pragma unroll
    for (int i = 0; i < 16; ++i) { acc0[i] = 0.f; acc1[i] = 0.f; acc2[i] = 0.f; acc3[i] = 0.f; }

    const float* bl_ = layer ? g_b2 : g_b1;
    const size_t lb = (((size_t)layer * 16) * 8 + wid) * 64 + lane;  // fragment idx at ks=0

#define WFRAG(W_, KS) (*(const s16x8*)((W_) + (lb + (size_t)(KS) * 512) * 8))
#define KSTEP(KS, BH, BL) do {                                                  \
      const int aoff_ = ((((KS) << 5) + (half << 4)) ^ ((cl & 7) << 4));        \
      s16x8 a0_ = *(const s16x8*)(sm +          cl * 512 + aoff_);              \
      s16x8 a1_ = *(const s16x8*)(sm + 16384 +  cl * 512 + aoff_);              \
      s16x8 a2_ = *(const s16x8*)(sm + 32768 +  cl * 512 + aoff_);              \
      s16x8 a3_ = *(const s16x8*)(sm + 49152 +  cl * 512 + aoff_);              \
      acc0 = __builtin_amdgcn_mfma_f32_32x32x16_bf16(a0_, BH, acc0, 0, 0, 0);   \
      acc0 = __builtin_amdgcn_mfma_f32_32x32x16_bf16(a0_, BL, acc0, 0, 0, 0);   \
      acc1 = __builtin_amdgcn_mfma_f32_32x32x16_bf16(a1_, BH, acc1, 0, 0, 0);   \
      acc1 = __builtin_amdgcn_mfma_f32_32x32x16_bf16(a1_, BL, acc1, 0, 0, 0);   \
      acc2 = __builtin_amdgcn_mfma_f32_32x32x16_bf16(a2_, BH, acc2, 0, 0, 0);   \
      acc2 = __builtin_amdgcn_mfma_f32_32x32x16_bf16(a2_, BL, acc2, 0, 0, 0);   \
      acc3 = __builtin_amdgcn_mfma_f32_32x32x16_bf16(a3_, BH, acc3, 0, 0, 0);   \
      acc3 = __builtin_amdgcn_mfma_f32_32x32x16_bf16(a3_, BL, acc3, 0, 0, 0);   \
    } while (0)

    s16x8 bh0 = WFRAG(wh, 0), bl0 = WFRAG(wl, 0);
    #pragma unroll
    for (int ks = 0; ks < 16; ks += 2) {
      s16x8 bh1 = WFRAG(wh, ks + 1);
      s16x8 bl1 = WFRAG(wl, ks + 1);
      KSTEP(ks, bh0, bl0);
      s16x8 bh2 = (ks + 2 < 16) ? WFRAG(wh, ks + 2) : bh1;
      s16x8 bl2 = (ks + 2 < 16) ? WFRAG(wl, ks + 2) : bl1;
      KSTEP(ks + 1, bh1, bl1);
      bh0 = bh2; bl0 = bl2;
    }
#undef KSTEP
#undef WFRAG
    __syncthreads();   // all x reads done before in-place overwrite

    const float bv   = bl_[(wid << 5) + cl];       // D col = wid*32 + cl
    const int   colb = (((wid << 5) + cl) << 1);

    if (layer == 0) {
      #pragma unroll
      for (int reg = 0; reg < 16; ++reg) {
        int rr  = (reg & 3) + ((reg >> 2) << 3) + (half << 2);
        int off = colb ^ ((rr & 7) << 4);
        *(unsigned short*)(sm +          rr * 512 + off) = f2bf(fmaxf(acc0[reg] + bv, 0.f));
        *(unsigned short*)(sm + 16384 +  rr * 512 + off) = f2bf(fmaxf(acc1[reg] + bv, 0.f));
        *(unsigned short*)(sm + 32768 +  rr * 512 + off) = f2bf(fmaxf(acc2[reg] + bv, 0.f));
        *(unsigned short*)(sm + 49152 +  rr * 512 + off) = f2bf(fmaxf(acc3[reg] + bv, 0.f));
      }
      __syncthreads();
    } else {
      // layer 2: per-row norm partials (over wave's 32 cols) + write p-hi
      #pragma unroll
      for (int reg = 0; reg < 16; ++reg) {
        int rr  = (reg & 3) + ((reg >> 2) << 3) + (half << 2);
        int off = colb ^ ((rr & 7) << 4);
        float p0 = acc0[reg] + bv, p1 = acc1[reg] + bv;
        float p2 = acc2[reg] + bv, p3 = acc3[reg] + bv;
        float s0 = xor16_add(row16_sum(p0 * p0));
        float s1 = xor16_add(row16_sum(p1 * p1));
        float s2 = xor16_add(row16_sum(p2 * p2));
        float s3 = xor16_add(row16_sum(p3 * p3));
        if (cl == 0) {
          normL[(0 * 8 + wid) * 32 + rr] = s0;
          normL[(1 * 8 + wid) * 32 + rr] = s1;
          normL[(2 * 8 + wid) * 32 + rr] = s2;
          normL[(3 * 8 + wid) * 32 + rr] = s3;
        }
        *(unsigned short*)(sm +          rr * 512 + off) = f2bf(p0);
        *(unsigned short*)(sm + 16384 +  rr * 512 + off) = f2bf(p1);
        *(unsigned short*)(sm + 32768 +  rr * 512 + off) = f2bf(p2);
        *(unsigned short*)(sm + 49152 +  rr * 512 + off) = f2bf(p3);
      }
      __syncthreads();
    }
  }

  // ---- G = pq @ pr^T: wave wid -> batch wid>>1, k-half wid&1 (4 ks16) ----
  const int fr = lane & 15, fg = lane >> 4;
  f32x4 accG = {0.f, 0.f, 0.f, 0.f};
  const int bbG = wid >> 1;
  {
    char* xb = sm + bbG * 16384;
    #pragma unroll
    for (int kk = 0; kk < 4; ++kk) {
      int ks16 = ((wid & 1) << 2) + kk;
      int koff = ((ks16 << 6) + (fg << 4)) ^ ((fr & 7) << 4);
      s16x8 aq = *(const s16x8*)(xb +        fr * 512 + koff);
      s16x8 br = *(const s16x8*)(xb + (16 + fr) * 512 + koff);
      accG = __builtin_amdgcn_mfma_f32_16x16x32_bf16(aq, br, accG, 0, 0, 0);
    }
  }
  __syncthreads();                       // all G-input reads complete
  float* Gp = smemf;                     // [4][2][256] overlays batch0 tile
  #pragma unroll
  for (int j = 0; j < 4; ++j)
    Gp[(bbG * 2 + (wid & 1)) * 256 + ((fg << 2) + j) * 16 + fr] = accG[j];
  __syncthreads();

  // ---- C = sqrt(max(nq + nr - 2G, 1e-6)); 2 outputs/thread ----
  #pragma unroll
  for (int s = 0; s < 2; ++s) {
    const int idx = (s << 9) + tid;      // 0..1023
    const int bbC = idx >> 8;
    const int t2  = idx & 255;
    const int tk  = t2 >> 4, tm = t2 & 15;
    float Gv = Gp[(bbC*2+0)*256 + tk*16 + tm] + Gp[(bbC*2+1)*256 + tk*16 + tm];
    float nq = 0.f, nr = 0.f;
    #pragma unroll
    for (int w = 0; w < 8; ++w) {
      nq += normL[(bbC*8+w)*32 + tk];
      nr += normL[(bbC*8+w)*32 + 16 + tm];
    }
    float d2 = nq + nr - 2.0f * Gv;
    g_out[OFF_C + (size_t)(bId0 + bbC) * 256 + t2] = sqrtf(fmaxf(d2, 1e-6f));
  }
}

// ---------------------------------------------------------------------------
// fgw_sink: 1 wave per batch, 4 waves/block, zero barriers.
// Lane layout: m = lane&15 (column), k_j = 4*(lane>>4)+j (4 rows per lane).
__global__ __launch_bounds__(256, 4)
void fgw_sink(const float* __restrict__ g_mq, const float* __restrict__ g_mr,
              const float* __restrict__ g_cq, const float* __restrict__ g_cr,
              const float* __restrict__ g_leps, float* __restrict__ g_out)
{
  __shared__ __align__(16) float sk[4 * 1408];
  const int tid  = threadIdx.x, lane = tid & 63, w = tid >> 6;
  const int batch = blockIdx.x * 4 + w;
  const int m = lane & 15, g = lane >> 4;
  float* L     = sk + w * 1408;
  float* SqL   = L;        float* SrL   = L + 320;
  float* TtL   = L + 640;  float* M1L   = L + 960;
  float* lmuL  = L + 1280; float* muL   = L + 1296;
  float* cqxL  = L + 1312; float* cqyL  = L + 1328;
  float* crxL  = L + 1344; float* cryL  = L + 1360;
  float* trowL = L + 1376; float* tcolL = L + 1392;

  float mqv = g_mq[(size_t)batch * 16 + m];
  float mrv = g_mr[(size_t)batch * 16 + m];
  float mu_m = mqv / (row16_sum(mqv) + 1e-8f);
  float nu_m = mrv / (row16_sum(mrv) + 1e-8f);
  float lmu_m = __logf(fmaxf(mu_m, 1e-8f));
  float lnu_m = __logf(fmaxf(nu_m, 1e-8f));
  float cqx_m = g_cq[(size_t)batch * 32 + 2 * m];
  float cqy_m = g_cq[(size_t)batch * 32 + 2 * m + 1];
  float crx_m = g_cr[(size_t)batch * 32 + 2 * m];
  float cry_m = g_cr[(size_t)batch * 32 + 2 * m + 1];
  if (g == 0) {
    lmuL[m] = lmu_m;  muL[m] = mu_m;
    cqxL[m] = cqx_m;  cqyL[m] = cqy_m;
    crxL[m] = crx_m;  cryL[m] = cry_m;
  }
  f32x4 lmu_j = *(const f32x4*)(lmuL + 4 * g);
  f32x4 mu_j  = *(const f32x4*)(muL  + 4 * g);
  f32x4 cqxj  = *(const f32x4*)(cqxL + 4 * g);
  f32x4 cqyj  = *(const f32x4*)(cqyL + 4 * g);
  f32x4 crxj  = *(const f32x4*)(crxL + 4 * g);
  f32x4 cryj  = *(const f32x4*)(cryL + 4 * g);

  float Sq2r[4], Sr2r[4];
  #pragma unroll
  for (int j = 0; j < 4; ++j) {
    float dx = cqxj[j] - cqx_m, dy = cqyj[j] - cqy_m;
    float d2 = fmaxf(dx * dx + dy * dy, 1e-6f);
    SqL[(4 * g + j) * 20 + m] = sqrtf(d2);
    Sq2r[j] = d2;
    float ex = crxj[j] - crx_m, ey = cryj[j] - cry_m;
    float e2 = fmaxf(ex * ex + ey * ey, 1e-6f);
    SrL[(4 * g + j) * 20 + m] = sqrtf(e2);
    Sr2r[j] = e2;
  }

  float C_[4];
  const float* Cp = g_out + OFF_C + (size_t)batch * 256;
  #pragma unroll
  for (int j = 0; j < 4; ++j) C_[j] = Cp[(4 * g + j) * 16 + m];
  float eps = fminf(fmaxf(__expf(g_leps[0]), 0.01f), 0.5f);
  const float inv_eps = 1.0f / eps;
  const float rho = 0.1f / (0.1f + eps);
  float rlmu[4];
  #pragma unroll
  for (int j = 0; j < 4; ++j) rlmu[j] = rho * lmu_j[j];
  const float rlnu = rho * lnu_m;
  float T_[4];
  #pragma unroll
  for (int j = 0; j < 4; ++j) T_[j] = mu_j[j] * nu_m;

  float Cf[4], logK[4], KM[4], Mx[4], u_[4], v = 0.f;

  for (int it = 0; it < 5; ++it) {
    float trow_j[4];
    #pragma unroll
    for (int j = 0; j < 4; ++j) trow_j[j] = row16_sum(T_[j]);
    float tc = xor32_add(xor16_add(T_[0] + T_[1] + T_[2] + T_[3]));
    if (m == 0) { f32x4 tv = {trow_j[0], trow_j[1], trow_j[2], trow_j[3]};
                  *(f32x4*)(trowL + 4 * g) = tv; }
    if (g == 0) tcolL[m] = tc;
    { f32x4 tv = {T_[0], T_[1], T_[2], T_[3]};
      *(f32x4*)(TtL + m * 20 + 4 * g) = tv; }

    float trow_m = trowL[m];
    float t1_[4];
    #pragma unroll
    for (int j = 0; j < 4; ++j) t1_[j] = row16_sum(Sq2r[j] * trow_m);
    f32x4 tcv = *(const f32x4*)(tcolL + 4 * g);
    float p2 = tcv[0] * Sr2r[0] + tcv[1] * Sr2r[1] + tcv[2] * Sr2r[2] + tcv[3] * Sr2r[3];
    float t2_ = xor32_add(xor16_add(p2));

    float M1r[4] = {0.f, 0.f, 0.f, 0.f};
    #pragma unroll
    for (int l = 0; l < 16; ++l) {
      f32x4 t4 = *(const f32x4*)(TtL + l * 20 + 4 * g);
      float srv = SrL[l * 20 + m];
      M1r[0] += t4[0] * srv; M1r[1] += t4[1] * srv;
      M1r[2] += t4[2] * srv; M1r[3] += t4[3] * srv;
    }
    #pragma unroll
    for (int j = 0; j < 4; ++j) M1L[(4 * g + j) * 20 + m] = M1r[j];
    float t3_[4] = {0.f, 0.f, 0.f, 0.f};
    #pragma unroll
    for (int l = 0; l < 16; ++l) {
      f32x4 sq4 = *(const f32x4*)(SqL + l * 20 + 4 * g);
      float m1v = M1L[l * 20 + m];
      t3_[0] += sq4[0] * m1v; t3_[1] += sq4[1] * m1v;
      t3_[2] += sq4[2] * m1v; t3_[3] += sq4[3] * m1v;
    }

    #pragma unroll
    for (int j = 0; j < 4; ++j) {
      float lgw = t1_[j] + t2_ - 2.0f * t3_[j];
      Cf[j]   = 0.5f * C_[j] + 0.5f * lgw;
      logK[j] = -inv_eps * Cf[j];
      Mx[j]   = row16_max(logK[j]);     // static row shift (underflow-safe)
      KM[j]   = logK[j] - Mx[j];
    }

    v = 0.f;
    #pragma unroll 1
    for (int s = 0; s < 10; ++s) {
      #pragma unroll
      for (int j = 0; j < 4; ++j) {
        float sj = row16_sum(__expf(KM[j] + v));
        u_[j] = rlmu[j] - rho * (Mx[j] + __logf(sj));
      }
      float x0 = logK[0] + u_[0], x1 = logK[1] + u_[1];
      float x2 = logK[2] + u_[2], x3 = logK[3] + u_[3];
      float mx = fmaxf(fmaxf(x0, x1), fmaxf(x2, x3));
      mx = xor32_max(xor16_max(mx));
      float ss = __expf(x0 - mx) + __expf(x1 - mx) + __expf(x2 - mx) + __expf(x3 - mx);
      ss = xor32_add(xor16_add(ss));
      v = rlnu - rho * (mx + __logf(ss));
    }
    #pragma unroll
    for (int j = 0; j < 4; ++j) T_[j] = __expf(u_[j] + logK[j] + v);
  }

  float cp = T_[0] * Cf[0] + T_[1] * Cf[1] + T_[2] * Cf[2] + T_[3] * Cf[3];
  cp = xor32_add(xor16_add(row16_sum(cp)));
  float* To = g_out + OFF_T + (size_t)batch * 256;
  #pragma unroll
  for (int j = 0; j < 4; ++j) To[(4 * g + j) * 16 + m] = T_[j];
  if (lane == 0) {
    g_out[batch] = 1.0f / (1.0f + __expf(cp));   // sigmoid(-cost)
    g_out[OFF_CST + batch] = cp;
  }
}

extern "C" void kernel_launch(void* const* d_in, const int* in_sizes, int n_in,
                              void* d_out, int out_size, void* d_ws, size_t ws_size,
                              hipStream_t stream) {
  (void)in_sizes; (void)n_in; (void)out_size; (void)ws_size;
  unsigned int*   wh32 = (unsigned int*)d_ws;
  unsigned int*   wl32 = wh32 + 65536;                 // 262,144 B each
  unsigned short* wh   = (unsigned short*)wh32;
  unsigned short* wl   = (unsigned short*)wl32;

  prep_w32<<<dim3(64), dim3(256), 0, stream>>>(
      (const float*)d_in[6], (const float*)d_in[8], wh32, wl32);
  fgw_proj<<<dim3(2048), dim3(512), 0, stream>>>(
      (const float*)d_in[0], (const float*)d_in[1], wh, wl,
      (const float*)d_in[7], (const float*)d_in[9], (float*)d_out);
  fgw_sink<<<dim3(2048), dim3(256), 0, stream>>>(
      (const float*)d_in[2], (const float*)d_in[3],
      (const float*)d_in[4], (const float*)d_in[5],
      (const float*)d_in[10], (float*)d_out);
}